// Round 1
// baseline (907.052 us; speedup 1.0000x reference)
//
#include <hip/hip_runtime.h>
#include <math.h>

#define LSEQ  512
#define BT    128
#define INF   512
#define HH    60
#define NSTEP 1536   // 3*LSEQ
#define CHUNK 24     // steps per lane in scan kernel: 1536 / 64

// ---------- rigid transform (3x3 rotation row-major + translation) ----------
struct Xf { float r[9]; float p[3]; };

__device__ __forceinline__ Xf compose(const Xf& A, const Xf& B) {
  // OUT = A ∘ B : R = Ra*Rb ; p = pa + Ra*pb
  Xf o;
#pragma unroll
  for (int i = 0; i < 3; ++i) {
#pragma unroll
    for (int j = 0; j < 3; ++j) {
      o.r[i*3+j] = fmaf(A.r[i*3+0], B.r[0+j],
                   fmaf(A.r[i*3+1], B.r[3+j],
                        A.r[i*3+2] * B.r[6+j]));
    }
    o.p[i] = fmaf(A.r[i*3+0], B.p[0],
             fmaf(A.r[i*3+1], B.p[1],
             fmaf(A.r[i*3+2], B.p[2], A.p[i])));
  }
  return o;
}

__device__ __forceinline__ Xf make_T(float phi, float st, float ct, float r) {
  float sp = __sinf(phi), cp = __cosf(phi);
  Xf T;
  T.r[0] = ct;      T.r[1] = -st;     T.r[2] = 0.f;
  T.r[3] = cp * st; T.r[4] = ct * cp; T.r[5] = -sp;
  T.r[6] = sp * st; T.r[7] = ct * sp; T.r[8] = cp;
  T.p[0] = r * ct;  T.p[1] = r * T.r[3]; T.p[2] = r * T.r[6];
  return T;
}

__device__ __forceinline__ void set_identity(Xf& X) {
  X.r[0]=1.f; X.r[1]=0.f; X.r[2]=0.f;
  X.r[3]=0.f; X.r[4]=1.f; X.r[5]=0.f;
  X.r[6]=0.f; X.r[7]=0.f; X.r[8]=1.f;
  X.p[0]=0.f; X.p[1]=0.f; X.p[2]=0.f;
}

// ---------- kernel 1: GEMM + softmax + torsion angles --------------------
// phi_out layout: (BT, NSTEP) so kernel 2 reads per-chain contiguously.
__global__ __launch_bounds__(256) void k_phi(
    const float* __restrict__ inp, const float* __restrict__ W,
    const float* __restrict__ bias, const float* __restrict__ alphabet,
    float* __restrict__ phi_out) {
  __shared__ float sA[HH*3], cA[HH*3];
  const int tid = threadIdx.x;
  if (tid < HH*3) { float a = alphabet[tid]; sA[tid] = __sinf(a); cA[tid] = __cosf(a); }
  __syncthreads();

  const int row = blockIdx.x * 256 + tid;           // 0 .. L*BT-1
  const float* ip = inp + (size_t)row * INF;

  float acc[HH];
#pragma unroll
  for (int h = 0; h < HH; ++h) acc[h] = bias[h];    // uniform -> scalar loads

#pragma unroll 2
  for (int kc = 0; kc < INF; kc += 8) {
    float4 v0 = *(const float4*)(ip + kc);
    float4 v1 = *(const float4*)(ip + kc + 4);
    float a0[8] = {v0.x, v0.y, v0.z, v0.w, v1.x, v1.y, v1.z, v1.w};
#pragma unroll
    for (int h = 0; h < HH; ++h) {
      const float* wr = W + h * INF + kc;           // wave-uniform address
#pragma unroll
      for (int i = 0; i < 8; ++i) acc[h] = fmaf(a0[i], wr[i], acc[h]);
    }
  }

  // unnormalized softmax (denominator cancels in atan2)
  float m = acc[0];
#pragma unroll
  for (int h = 1; h < HH; ++h) m = fmaxf(m, acc[h]);
  float s0=0.f, c0=0.f, s1=0.f, c1=0.f, s2=0.f, c2=0.f;
#pragma unroll
  for (int h = 0; h < HH; ++h) {
    float x = __expf(acc[h] - m);
    s0 = fmaf(x, sA[h*3+0], s0);  c0 = fmaf(x, cA[h*3+0], c0);
    s1 = fmaf(x, sA[h*3+1], s1);  c1 = fmaf(x, cA[h*3+1], c1);
    s2 = fmaf(x, sA[h*3+2], s2);  c2 = fmaf(x, cA[h*3+2], c2);
  }
  const int l  = row >> 7;        // / BT
  const int bb = row & 127;       // % BT
  float* pp = phi_out + (size_t)bb * NSTEP + 3 * l;
  pp[0] = atan2f(s0, c0);
  pp[1] = atan2f(s1, c1);
  pp[2] = atan2f(s2, c2);
}

// ---------- kernel 2: parallel rigid-transform scan -----------------------
// One wave (64 lanes) per chain b. Lane t owns steps [24t, 24t+24).
__global__ __launch_bounds__(64) void k_scan(
    const float* __restrict__ phi, const float* __restrict__ bl,
    const float* __restrict__ ba, float* __restrict__ out) {
  const int b = blockIdx.x;       // chain 0..127
  const int t = threadIdx.x;      // lane 0..63

  float st[3], ct[3], rr[3];
#pragma unroll
  for (int j = 0; j < 3; ++j) {
    float a = ba[j];
    st[j] = __sinf(a); ct[j] = __cosf(a); rr[j] = bl[j];
  }

  float f[CHUNK];
  const float4* ph4 = (const float4*)(phi + (size_t)b * NSTEP + t * CHUNK);
#pragma unroll
  for (int q = 0; q < CHUNK/4; ++q) {
    float4 v = ph4[q];
    f[4*q+0] = v.x; f[4*q+1] = v.y; f[4*q+2] = v.z; f[4*q+3] = v.w;
  }

  // local chunk product Q = T_{24t} ∘ ... ∘ T_{24t+23}   (24t ≡ 0 mod 3)
  Xf Q = make_T(f[0], st[0], ct[0], rr[0]);
#pragma unroll
  for (int s = 1; s < CHUNK; ++s)
    Q = compose(Q, make_T(f[s], st[s%3], ct[s%3], rr[s%3]));

  // wave-level inclusive scan (Hillis-Steele, associative non-commutative op)
#pragma unroll
  for (int d = 1; d < 64; d <<= 1) {
    Xf O;
#pragma unroll
    for (int q = 0; q < 9; ++q) O.r[q] = __shfl_up(Q.r[q], d, 64);
#pragma unroll
    for (int q = 0; q < 3; ++q) O.p[q] = __shfl_up(Q.p[q], d, 64);
    if (t < d) set_identity(O);
    Q = compose(O, Q);
  }

  // exclusive prefix for this lane
  Xf E;
#pragma unroll
  for (int q = 0; q < 9; ++q) E.r[q] = __shfl_up(Q.r[q], 1, 64);
#pragma unroll
  for (int q = 0; q < 3; ++q) E.p[q] = __shfl_up(Q.p[q], 1, 64);
  if (t == 0) set_identity(E);

  // seed frame from carry0 = (e0, e1, e2):
  // R0 columns = [bc0, n0 x bc0 ... wait m0, n0], p0 = (0,0,1)
  Xf S0;
  S0.r[0] = 0.f;                 S0.r[1] = 0.816496580927726f;  S0.r[2] = 0.5773502691896258f;
  S0.r[3] = -0.7071067811865475f; S0.r[4] = -0.4082482904638631f; S0.r[5] = 0.5773502691896258f;
  S0.r[6] = 0.7071067811865475f;  S0.r[7] = -0.4082482904638631f; S0.r[8] = 0.5773502691896258f;
  S0.p[0] = 0.f; S0.p[1] = 0.f; S0.p[2] = 1.f;

  Xf cur = compose(S0, E);

  // re-apply local transforms, emit atom positions
  float* op = out + (size_t)(t * CHUNK) * (BT * 3) + b * 3;
#pragma unroll
  for (int s = 0; s < CHUNK; ++s) {
    cur = compose(cur, make_T(f[s], st[s%3], ct[s%3], rr[s%3]));
    op[(size_t)s * (BT*3) + 0] = cur.p[0];
    op[(size_t)s * (BT*3) + 1] = cur.p[1];
    op[(size_t)s * (BT*3) + 2] = cur.p[2];
  }
}

// ---------- launch ---------------------------------------------------------
extern "C" void kernel_launch(void* const* d_in, const int* in_sizes, int n_in,
                              void* d_out, int out_size, void* d_ws, size_t ws_size,
                              hipStream_t stream) {
  const float* inp      = (const float*)d_in[0];
  const float* W        = (const float*)d_in[1];
  const float* bias     = (const float*)d_in[2];
  const float* alphabet = (const float*)d_in[3];
  const float* bl       = (const float*)d_in[4];
  const float* ba       = (const float*)d_in[5];
  float* out = (float*)d_out;
  float* phi = (float*)d_ws;    // (BT, NSTEP) = 786432 bytes

  k_phi<<<dim3((LSEQ*BT)/256), dim3(256), 0, stream>>>(inp, W, bias, alphabet, phi);
  k_scan<<<dim3(BT), dim3(64), 0, stream>>>(phi, bl, ba, out);
}

// Round 2
// 546.241 us; speedup vs baseline: 1.6605x; 1.6605x over previous
//
#include <hip/hip_runtime.h>
#include <math.h>

#define LSEQ  512
#define BT    128
#define INF   512
#define HH    60
#define NSTEP 1536   // 3*LSEQ
#define CHUNK 24     // steps per lane in scan kernel: 1536 / 64
#define RSTRIDE 61   // odd stride -> at worst 2-way LDS bank aliasing (free)

// ---------- rigid transform (3x3 rotation row-major + translation) ----------
struct Xf { float r[9]; float p[3]; };

__device__ __forceinline__ Xf compose(const Xf& A, const Xf& B) {
  Xf o;
#pragma unroll
  for (int i = 0; i < 3; ++i) {
#pragma unroll
    for (int j = 0; j < 3; ++j) {
      o.r[i*3+j] = fmaf(A.r[i*3+0], B.r[0+j],
                   fmaf(A.r[i*3+1], B.r[3+j],
                        A.r[i*3+2] * B.r[6+j]));
    }
    o.p[i] = fmaf(A.r[i*3+0], B.p[0],
             fmaf(A.r[i*3+1], B.p[1],
             fmaf(A.r[i*3+2], B.p[2], A.p[i])));
  }
  return o;
}

__device__ __forceinline__ Xf make_T(float phi, float st, float ct, float r) {
  float sp = __sinf(phi), cp = __cosf(phi);
  Xf T;
  T.r[0] = ct;      T.r[1] = -st;     T.r[2] = 0.f;
  T.r[3] = cp * st; T.r[4] = ct * cp; T.r[5] = -sp;
  T.r[6] = sp * st; T.r[7] = ct * sp; T.r[8] = cp;
  T.p[0] = r * ct;  T.p[1] = r * T.r[3]; T.p[2] = r * T.r[6];
  return T;
}

__device__ __forceinline__ void set_identity(Xf& X) {
  X.r[0]=1.f; X.r[1]=0.f; X.r[2]=0.f;
  X.r[3]=0.f; X.r[4]=1.f; X.r[5]=0.f;
  X.r[6]=0.f; X.r[7]=0.f; X.r[8]=1.f;
  X.p[0]=0.f; X.p[1]=0.f; X.p[2]=0.f;
}

// ---------- kernel 1: GEMM + softmax + torsion angles --------------------
// Block = 256 threads = 4 waves. Wave w owns K-chunk [128w, 128w+128).
// Lane l owns row blockIdx.x*64 + l. W addresses are wave-uniform -> s_load.
// Partials reduced across waves through LDS (stride 61 = odd, conflict-free).
__global__ __launch_bounds__(256, 2) void k_phi(
    const float* __restrict__ inp, const float* __restrict__ W,
    const float* __restrict__ bias, const float* __restrict__ alphabet,
    float* __restrict__ phi_out) {
  __shared__ float red[3 * 64 * RSTRIDE];   // partials of waves 1..3 (~46.8 KB)

  const int tid  = threadIdx.x;
  const int lane = tid & 63;
  const int wid  = __builtin_amdgcn_readfirstlane(tid >> 6);  // 0..3, SGPR
  const int row  = blockIdx.x * 64 + lane;                    // 0 .. L*BT-1
  const int kb   = wid * 128;                                 // SGPR

  const float* ip = inp + (size_t)row * INF + kb;

  float acc[HH];
#pragma unroll
  for (int h = 0; h < HH; ++h) acc[h] = 0.f;

  for (int k0 = 0; k0 < 128; k0 += 16) {
    float4 v0 = *(const float4*)(ip + k0 + 0);
    float4 v1 = *(const float4*)(ip + k0 + 4);
    float4 v2 = *(const float4*)(ip + k0 + 8);
    float4 v3 = *(const float4*)(ip + k0 + 12);
    float a[16] = {v0.x, v0.y, v0.z, v0.w, v1.x, v1.y, v1.z, v1.w,
                   v2.x, v2.y, v2.z, v2.w, v3.x, v3.y, v3.z, v3.w};
#pragma unroll
    for (int h = 0; h < HH; ++h) {
      const float* wr = W + h * INF + kb + k0;   // wave-uniform -> s_load
#pragma unroll
      for (int i = 0; i < 16; ++i) acc[h] = fmaf(a[i], wr[i], acc[h]);
    }
  }

  if (wid != 0) {
    float* dst = red + (wid - 1) * 64 * RSTRIDE + lane * RSTRIDE;
#pragma unroll
    for (int h = 0; h < HH; ++h) dst[h] = acc[h];
  }
  __syncthreads();

  if (wid == 0) {
#pragma unroll
    for (int w = 0; w < 3; ++w) {
      const float* src = red + w * 64 * RSTRIDE + lane * RSTRIDE;
#pragma unroll
      for (int h = 0; h < HH; ++h) acc[h] += src[h];
    }
#pragma unroll
    for (int h = 0; h < HH; ++h) acc[h] += bias[h];   // uniform scalar loads

    // unnormalized softmax (denominator cancels in atan2)
    float m = acc[0];
#pragma unroll
    for (int h = 1; h < HH; ++h) m = fmaxf(m, acc[h]);
    float s0=0.f, c0=0.f, s1=0.f, c1=0.f, s2=0.f, c2=0.f;
#pragma unroll
    for (int h = 0; h < HH; ++h) {
      float x = __expf(acc[h] - m);
      float a0 = alphabet[h*3+0], a1 = alphabet[h*3+1], a2 = alphabet[h*3+2];
      s0 = fmaf(x, __sinf(a0), s0);  c0 = fmaf(x, __cosf(a0), c0);
      s1 = fmaf(x, __sinf(a1), s1);  c1 = fmaf(x, __cosf(a1), c1);
      s2 = fmaf(x, __sinf(a2), s2);  c2 = fmaf(x, __cosf(a2), c2);
    }
    const int l  = row >> 7;        // / BT
    const int bb = row & 127;       // % BT
    float* pp = phi_out + (size_t)bb * NSTEP + 3 * l;
    pp[0] = atan2f(s0, c0);
    pp[1] = atan2f(s1, c1);
    pp[2] = atan2f(s2, c2);
  }
}

// ---------- kernel 2: parallel rigid-transform scan -----------------------
// One wave (64 lanes) per chain b. Lane t owns steps [24t, 24t+24).
__global__ __launch_bounds__(64) void k_scan(
    const float* __restrict__ phi, const float* __restrict__ bl,
    const float* __restrict__ ba, float* __restrict__ out) {
  const int b = blockIdx.x;       // chain 0..127
  const int t = threadIdx.x;      // lane 0..63

  float st[3], ct[3], rr[3];
#pragma unroll
  for (int j = 0; j < 3; ++j) {
    float a = ba[j];
    st[j] = __sinf(a); ct[j] = __cosf(a); rr[j] = bl[j];
  }

  float f[CHUNK];
  const float4* ph4 = (const float4*)(phi + (size_t)b * NSTEP + t * CHUNK);
#pragma unroll
  for (int q = 0; q < CHUNK/4; ++q) {
    float4 v = ph4[q];
    f[4*q+0] = v.x; f[4*q+1] = v.y; f[4*q+2] = v.z; f[4*q+3] = v.w;
  }

  // local chunk product Q = T_{24t} ∘ ... ∘ T_{24t+23}
  Xf Q = make_T(f[0], st[0], ct[0], rr[0]);
#pragma unroll
  for (int s = 1; s < CHUNK; ++s)
    Q = compose(Q, make_T(f[s], st[s%3], ct[s%3], rr[s%3]));

  // wave-level inclusive scan (Hillis-Steele)
#pragma unroll
  for (int d = 1; d < 64; d <<= 1) {
    Xf O;
#pragma unroll
    for (int q = 0; q < 9; ++q) O.r[q] = __shfl_up(Q.r[q], d, 64);
#pragma unroll
    for (int q = 0; q < 3; ++q) O.p[q] = __shfl_up(Q.p[q], d, 64);
    if (t < d) set_identity(O);
    Q = compose(O, Q);
  }

  // exclusive prefix for this lane
  Xf E;
#pragma unroll
  for (int q = 0; q < 9; ++q) E.r[q] = __shfl_up(Q.r[q], 1, 64);
#pragma unroll
  for (int q = 0; q < 3; ++q) E.p[q] = __shfl_up(Q.p[q], 1, 64);
  if (t == 0) set_identity(E);

  // seed frame from carry0 = (e0, e1, e2)
  Xf S0;
  S0.r[0] = 0.f;                  S0.r[1] = 0.816496580927726f;   S0.r[2] = 0.5773502691896258f;
  S0.r[3] = -0.7071067811865475f; S0.r[4] = -0.4082482904638631f; S0.r[5] = 0.5773502691896258f;
  S0.r[6] = 0.7071067811865475f;  S0.r[7] = -0.4082482904638631f; S0.r[8] = 0.5773502691896258f;
  S0.p[0] = 0.f; S0.p[1] = 0.f; S0.p[2] = 1.f;

  Xf cur = compose(S0, E);

  // re-apply local transforms, emit atom positions
  float* op = out + (size_t)(t * CHUNK) * (BT * 3) + b * 3;
#pragma unroll
  for (int s = 0; s < CHUNK; ++s) {
    cur = compose(cur, make_T(f[s], st[s%3], ct[s%3], rr[s%3]));
    op[(size_t)s * (BT*3) + 0] = cur.p[0];
    op[(size_t)s * (BT*3) + 1] = cur.p[1];
    op[(size_t)s * (BT*3) + 2] = cur.p[2];
  }
}

// ---------- launch ---------------------------------------------------------
extern "C" void kernel_launch(void* const* d_in, const int* in_sizes, int n_in,
                              void* d_out, int out_size, void* d_ws, size_t ws_size,
                              hipStream_t stream) {
  const float* inp      = (const float*)d_in[0];
  const float* W        = (const float*)d_in[1];
  const float* bias     = (const float*)d_in[2];
  const float* alphabet = (const float*)d_in[3];
  const float* bl       = (const float*)d_in[4];
  const float* ba       = (const float*)d_in[5];
  float* out = (float*)d_out;
  float* phi = (float*)d_ws;    // (BT, NSTEP) floats = 786432 bytes

  k_phi<<<dim3((LSEQ*BT)/64), dim3(256), 0, stream>>>(inp, W, bias, alphabet, phi);
  k_scan<<<dim3(BT), dim3(64), 0, stream>>>(phi, bl, ba, out);
}

// Round 3
// 379.662 us; speedup vs baseline: 2.3891x; 1.4388x over previous
//
#include <hip/hip_runtime.h>
#include <math.h>

#define LSEQ  512
#define BT    128
#define INF   512
#define HH    60
#define NSTEP 1536   // 3*LSEQ
#define CHUNK 24     // steps per lane in scan kernel: 1536 / 64

#define MT    64     // rows per block in k_phi
#define KT    128    // K-tile
#define LROW  132    // KT + 4 pad: keeps 16B alignment, conflict-free b128

// ---------- rigid transform (3x3 rotation row-major + translation) ----------
struct Xf { float r[9]; float p[3]; };

__device__ __forceinline__ Xf compose(const Xf& A, const Xf& B) {
  Xf o;
#pragma unroll
  for (int i = 0; i < 3; ++i) {
#pragma unroll
    for (int j = 0; j < 3; ++j) {
      o.r[i*3+j] = fmaf(A.r[i*3+0], B.r[0+j],
                   fmaf(A.r[i*3+1], B.r[3+j],
                        A.r[i*3+2] * B.r[6+j]));
    }
    o.p[i] = fmaf(A.r[i*3+0], B.p[0],
             fmaf(A.r[i*3+1], B.p[1],
             fmaf(A.r[i*3+2], B.p[2], A.p[i])));
  }
  return o;
}

__device__ __forceinline__ Xf make_T(float phi, float st, float ct, float r) {
  float sp = __sinf(phi), cp = __cosf(phi);
  Xf T;
  T.r[0] = ct;      T.r[1] = -st;     T.r[2] = 0.f;
  T.r[3] = cp * st; T.r[4] = ct * cp; T.r[5] = -sp;
  T.r[6] = sp * st; T.r[7] = ct * sp; T.r[8] = cp;
  T.p[0] = r * ct;  T.p[1] = r * T.r[3]; T.p[2] = r * T.r[6];
  return T;
}

__device__ __forceinline__ void set_identity(Xf& X) {
  X.r[0]=1.f; X.r[1]=0.f; X.r[2]=0.f;
  X.r[3]=0.f; X.r[4]=1.f; X.r[5]=0.f;
  X.r[6]=0.f; X.r[7]=0.f; X.r[8]=1.f;
  X.p[0]=0.f; X.p[1]=0.f; X.p[2]=0.f;
}

// ---------- kernel 1: GEMM + softmax + torsion angles ----------------------
// Block: 256 threads = 4 waves, 64 rows. Wave w computes h in [15w, 15w+15)
// for all 64 rows (lane = row). W addresses wave-uniform -> s_load (SGPR).
// inp staged via LDS tiles; only 15 accumulators/thread -> no spill.
__global__ __launch_bounds__(256, 4) void k_phi(
    const float* __restrict__ inp, const float* __restrict__ W,
    const float* __restrict__ bias, const float* __restrict__ alphabet,
    float* __restrict__ phi_out) {
  __shared__ float sTile[MT * LROW];   // 33792 B; reused for h-gather later
  __shared__ float sS[HH * 3], sC[HH * 3];

  const int tid  = threadIdx.x;
  const int lane = tid & 63;
  const int wid  = __builtin_amdgcn_readfirstlane(tid >> 6);  // 0..3
  const int row0 = blockIdx.x * MT;

  if (tid < HH * 3) {
    float a = alphabet[tid];
    sS[tid] = __sinf(a); sC[tid] = __cosf(a);
  }

  float acc[15];
#pragma unroll
  for (int j = 0; j < 15; ++j) acc[j] = 0.f;

  const int ldr = tid >> 5;         // 0..7  row-group for staging
  const int ldc = (tid & 31) * 4;   // col for staging

  for (int t = 0; t < 4; ++t) {
    const int k0 = t * KT;
    // stage 64 x 128 tile of inp (coalesced float4)
#pragma unroll
    for (int rep = 0; rep < 8; ++rep) {
      const int r = rep * 8 + ldr;
      float4 v = *(const float4*)(inp + (size_t)(row0 + r) * INF + k0 + ldc);
      *(float4*)&sTile[r * LROW + ldc] = v;
    }
    __syncthreads();

    const float* wbase = W + (size_t)(wid * 15) * INF + k0;   // SGPR
#pragma unroll 8
    for (int k = 0; k < KT; k += 4) {
      float4 x = *(const float4*)&sTile[lane * LROW + k];     // ds_read_b128
#pragma unroll
      for (int j = 0; j < 15; ++j) {
        const float* wr = wbase + j * INF + k;                // s_load
        acc[j] = fmaf(x.x, wr[0], acc[j]);
        acc[j] = fmaf(x.y, wr[1], acc[j]);
        acc[j] = fmaf(x.z, wr[2], acc[j]);
        acc[j] = fmaf(x.w, wr[3], acc[j]);
      }
    }
    __syncthreads();   // also protects sTile reuse below
  }

  // gather all 60 h per row into reused sTile (stride 61: odd -> free)
  {
    float* dst = sTile + lane * 61 + wid * 15;
#pragma unroll
    for (int j = 0; j < 15; ++j) dst[j] = acc[j];
  }
  __syncthreads();

  if (wid == 0) {
    const float* v = sTile + lane * 61;
    // pass 1: max of logits (+bias)
    float m = -1e30f;
#pragma unroll
    for (int h = 0; h < HH; ++h) m = fmaxf(m, v[h] + bias[h]);
    // pass 2: unnormalized softmax -> weighted sin/cos (denominator cancels)
    float s0=0.f, c0=0.f, s1=0.f, c1=0.f, s2=0.f, c2=0.f;
#pragma unroll
    for (int h = 0; h < HH; ++h) {
      float x = __expf(v[h] + bias[h] - m);
      s0 = fmaf(x, sS[h*3+0], s0);  c0 = fmaf(x, sC[h*3+0], c0);
      s1 = fmaf(x, sS[h*3+1], s1);  c1 = fmaf(x, sC[h*3+1], c1);
      s2 = fmaf(x, sS[h*3+2], s2);  c2 = fmaf(x, sC[h*3+2], c2);
    }
    const int row = row0 + lane;
    const int l  = row >> 7;        // / BT
    const int bb = row & 127;       // % BT
    float* pp = phi_out + (size_t)bb * NSTEP + 3 * l;
    pp[0] = atan2f(s0, c0);
    pp[1] = atan2f(s1, c1);
    pp[2] = atan2f(s2, c2);
  }
}

// ---------- kernel 2: parallel rigid-transform scan ------------------------
// One wave (64 lanes) per chain b. Lane t owns steps [24t, 24t+24).
__global__ __launch_bounds__(64) void k_scan(
    const float* __restrict__ phi, const float* __restrict__ bl,
    const float* __restrict__ ba, float* __restrict__ out) {
  const int b = blockIdx.x;       // chain 0..127
  const int t = threadIdx.x;      // lane 0..63

  float st[3], ct[3], rr[3];
#pragma unroll
  for (int j = 0; j < 3; ++j) {
    float a = ba[j];
    st[j] = __sinf(a); ct[j] = __cosf(a); rr[j] = bl[j];
  }

  float f[CHUNK];
  const float4* ph4 = (const float4*)(phi + (size_t)b * NSTEP + t * CHUNK);
#pragma unroll
  for (int q = 0; q < CHUNK/4; ++q) {
    float4 v = ph4[q];
    f[4*q+0] = v.x; f[4*q+1] = v.y; f[4*q+2] = v.z; f[4*q+3] = v.w;
  }

  // local chunk product
  Xf Q = make_T(f[0], st[0], ct[0], rr[0]);
#pragma unroll
  for (int s = 1; s < CHUNK; ++s)
    Q = compose(Q, make_T(f[s], st[s%3], ct[s%3], rr[s%3]));

  // wave-level inclusive scan (Hillis-Steele)
#pragma unroll
  for (int d = 1; d < 64; d <<= 1) {
    Xf O;
#pragma unroll
    for (int q = 0; q < 9; ++q) O.r[q] = __shfl_up(Q.r[q], d, 64);
#pragma unroll
    for (int q = 0; q < 3; ++q) O.p[q] = __shfl_up(Q.p[q], d, 64);
    if (t < d) set_identity(O);
    Q = compose(O, Q);
  }

  // exclusive prefix
  Xf E;
#pragma unroll
  for (int q = 0; q < 9; ++q) E.r[q] = __shfl_up(Q.r[q], 1, 64);
#pragma unroll
  for (int q = 0; q < 3; ++q) E.p[q] = __shfl_up(Q.p[q], 1, 64);
  if (t == 0) set_identity(E);

  // seed frame from carry0 = (e0, e1, e2)
  Xf S0;
  S0.r[0] = 0.f;                  S0.r[1] = 0.816496580927726f;   S0.r[2] = 0.5773502691896258f;
  S0.r[3] = -0.7071067811865475f; S0.r[4] = -0.4082482904638631f; S0.r[5] = 0.5773502691896258f;
  S0.r[6] = 0.7071067811865475f;  S0.r[7] = -0.4082482904638631f; S0.r[8] = 0.5773502691896258f;
  S0.p[0] = 0.f; S0.p[1] = 0.f; S0.p[2] = 1.f;

  Xf cur = compose(S0, E);

  float* op = out + (size_t)(t * CHUNK) * (BT * 3) + b * 3;
#pragma unroll
  for (int s = 0; s < CHUNK; ++s) {
    cur = compose(cur, make_T(f[s], st[s%3], ct[s%3], rr[s%3]));
    op[(size_t)s * (BT*3) + 0] = cur.p[0];
    op[(size_t)s * (BT*3) + 1] = cur.p[1];
    op[(size_t)s * (BT*3) + 2] = cur.p[2];
  }
}

// ---------- launch ---------------------------------------------------------
extern "C" void kernel_launch(void* const* d_in, const int* in_sizes, int n_in,
                              void* d_out, int out_size, void* d_ws, size_t ws_size,
                              hipStream_t stream) {
  const float* inp      = (const float*)d_in[0];
  const float* W        = (const float*)d_in[1];
  const float* bias     = (const float*)d_in[2];
  const float* alphabet = (const float*)d_in[3];
  const float* bl       = (const float*)d_in[4];
  const float* ba       = (const float*)d_in[5];
  float* out = (float*)d_out;
  float* phi = (float*)d_ws;    // (BT, NSTEP) floats = 786432 bytes

  k_phi<<<dim3((LSEQ*BT)/MT), dim3(256), 0, stream>>>(inp, W, bias, alphabet, phi);
  k_scan<<<dim3(BT), dim3(64), 0, stream>>>(phi, bl, ba, out);
}

// Round 4
// 259.177 us; speedup vs baseline: 3.4997x; 1.4649x over previous
//
#include <hip/hip_runtime.h>
#include <math.h>

#define LSEQ  512
#define BT    128
#define INF   512
#define HH    60
#define NSTEP 1536   // 3*LSEQ
#define CHUNK 24     // steps per lane in scan kernel: 1536 / 64

#define MT2   128    // rows per block in k_phi
#define KT    64     // K-tile
#define KG    16     // KT/4 float4 k-groups
#define AP    129    // 128 rows + 1 pad (float4 units): stride-129 writes = 2-way (free)

// ---------- rigid transform (3x3 rotation row-major + translation) ----------
struct Xf { float r[9]; float p[3]; };

__device__ __forceinline__ Xf compose(const Xf& A, const Xf& B) {
  Xf o;
#pragma unroll
  for (int i = 0; i < 3; ++i) {
#pragma unroll
    for (int j = 0; j < 3; ++j) {
      o.r[i*3+j] = fmaf(A.r[i*3+0], B.r[0+j],
                   fmaf(A.r[i*3+1], B.r[3+j],
                        A.r[i*3+2] * B.r[6+j]));
    }
    o.p[i] = fmaf(A.r[i*3+0], B.p[0],
             fmaf(A.r[i*3+1], B.p[1],
             fmaf(A.r[i*3+2], B.p[2], A.p[i])));
  }
  return o;
}

__device__ __forceinline__ Xf make_T(float phi, float st, float ct, float r) {
  float sp = __sinf(phi), cp = __cosf(phi);
  Xf T;
  T.r[0] = ct;      T.r[1] = -st;     T.r[2] = 0.f;
  T.r[3] = cp * st; T.r[4] = ct * cp; T.r[5] = -sp;
  T.r[6] = sp * st; T.r[7] = ct * sp; T.r[8] = cp;
  T.p[0] = r * ct;  T.p[1] = r * T.r[3]; T.p[2] = r * T.r[6];
  return T;
}

__device__ __forceinline__ void set_identity(Xf& X) {
  X.r[0]=1.f; X.r[1]=0.f; X.r[2]=0.f;
  X.r[3]=0.f; X.r[4]=1.f; X.r[5]=0.f;
  X.r[6]=0.f; X.r[7]=0.f; X.r[8]=1.f;
  X.p[0]=0.f; X.p[1]=0.f; X.p[2]=0.f;
}

// ---------- kernel 1: GEMM + softmax + torsion angles ----------------------
// Block: 256 threads = 4 waves. Tile: 128 rows x 60 h. Thread = 2 rows x 15 h.
// Wave w owns h in [15w,15w+15) -> W reads are wave-uniform (LDS broadcast).
// A tile in LDS as float4[kgroup][129] (reads conflict-free, writes 2-way=free).
__global__ __launch_bounds__(256, 3) void k_phi(
    const float* __restrict__ inp, const float* __restrict__ W,
    const float* __restrict__ bias, const float* __restrict__ alphabet,
    float* __restrict__ phi_out) {
  __shared__ float4 A4[KG * AP];     // 33 KB; reused as red[] in epilogue
  __shared__ float4 W4[HH * KG];     // 15.4 KB, layout [h][kgroup]
  __shared__ float sS[HH * 3], sC[HH * 3];

  const int tid   = threadIdx.x;
  const int lane  = tid & 63;
  const int wid   = __builtin_amdgcn_readfirstlane(tid >> 6);  // 0..3
  const int hbase = wid * 15;
  const int row0  = blockIdx.x * MT2;

  if (tid < HH * 3) {
    float a = alphabet[tid];
    sS[tid] = __sinf(a); sC[tid] = __cosf(a);
  }

  float acc0[15], acc1[15];
#pragma unroll
  for (int j = 0; j < 15; ++j) { acc0[j] = 0.f; acc1[j] = 0.f; }

  for (int t = 0; t < INF / KT; ++t) {
    const int k0 = t * KT;
    // ---- stage A: 128 rows x 64 k  (2048 float4, 8 per thread) ----
#pragma unroll
    for (int i = 0; i < 8; ++i) {
      const int idx = i * 256 + tid;
      const int g = idx & 15;          // k-group (fastest -> coalesced global)
      const int r = idx >> 4;          // row
      float4 v = *(const float4*)(inp + (size_t)(row0 + r) * INF + k0 + 4 * g);
      A4[g * AP + r] = v;
    }
    // ---- stage W: 60 h x 64 k (960 float4) ----
#pragma unroll
    for (int i = 0; i < 4; ++i) {
      const int idx = i * 256 + tid;
      if (idx < HH * KG) {
        const int g = idx & 15;
        const int h = idx >> 4;
        float4 v = *(const float4*)(W + (size_t)h * INF + k0 + 4 * g);
        W4[h * KG + g] = v;
      }
    }
    __syncthreads();

    // ---- compute: per k-group 17 LDS reads -> 120 FMAs ----
    for (int g = 0; g < KG; ++g) {
      float4 xa = A4[g * AP + lane];
      float4 xb = A4[g * AP + 64 + lane];
#pragma unroll
      for (int j = 0; j < 15; ++j) {
        float4 wv = W4[(hbase + j) * KG + g];   // wave-uniform -> broadcast
        acc0[j] = fmaf(xa.x, wv.x, acc0[j]);
        acc0[j] = fmaf(xa.y, wv.y, acc0[j]);
        acc0[j] = fmaf(xa.z, wv.z, acc0[j]);
        acc0[j] = fmaf(xa.w, wv.w, acc0[j]);
        acc1[j] = fmaf(xb.x, wv.x, acc1[j]);
        acc1[j] = fmaf(xb.y, wv.y, acc1[j]);
        acc1[j] = fmaf(xb.z, wv.z, acc1[j]);
        acc1[j] = fmaf(xb.w, wv.w, acc1[j]);
      }
    }
    __syncthreads();
  }

  // ---- gather 60 h per row into reused A4 buffer (stride 61, odd -> free) --
  float* red = (float*)A4;
  {
    float* d0 = red + lane * 61 + hbase;
    float* d1 = red + (lane + 64) * 61 + hbase;
#pragma unroll
    for (int j = 0; j < 15; ++j) { d0[j] = acc0[j]; d1[j] = acc1[j]; }
  }
  __syncthreads();

  // ---- epilogue: waves 0,1 handle 128 rows -----------------------------
  if (wid < 2) {
    const int row = wid * 64 + lane;
    const float* v = red + row * 61;
    float m = -1e30f;
#pragma unroll
    for (int h = 0; h < HH; ++h) m = fmaxf(m, v[h] + bias[h]);
    float s0=0.f, c0=0.f, s1=0.f, c1=0.f, s2=0.f, c2=0.f;
#pragma unroll
    for (int h = 0; h < HH; ++h) {
      float x = __expf(v[h] + bias[h] - m);
      s0 = fmaf(x, sS[h*3+0], s0);  c0 = fmaf(x, sC[h*3+0], c0);
      s1 = fmaf(x, sS[h*3+1], s1);  c1 = fmaf(x, sC[h*3+1], c1);
      s2 = fmaf(x, sS[h*3+2], s2);  c2 = fmaf(x, sC[h*3+2], c2);
    }
    const int grow = row0 + row;
    const int l  = grow >> 7;        // / BT
    const int bb = grow & 127;       // % BT
    float* pp = phi_out + (size_t)bb * NSTEP + 3 * l;
    pp[0] = atan2f(s0, c0);
    pp[1] = atan2f(s1, c1);
    pp[2] = atan2f(s2, c2);
  }
}

// ---------- kernel 2: parallel rigid-transform scan ------------------------
// One wave (64 lanes) per chain b. Lane t owns steps [24t, 24t+24).
__global__ __launch_bounds__(64) void k_scan(
    const float* __restrict__ phi, const float* __restrict__ bl,
    const float* __restrict__ ba, float* __restrict__ out) {
  const int b = blockIdx.x;       // chain 0..127
  const int t = threadIdx.x;      // lane 0..63

  float st[3], ct[3], rr[3];
#pragma unroll
  for (int j = 0; j < 3; ++j) {
    float a = ba[j];
    st[j] = __sinf(a); ct[j] = __cosf(a); rr[j] = bl[j];
  }

  float f[CHUNK];
  const float4* ph4 = (const float4*)(phi + (size_t)b * NSTEP + t * CHUNK);
#pragma unroll
  for (int q = 0; q < CHUNK/4; ++q) {
    float4 v = ph4[q];
    f[4*q+0] = v.x; f[4*q+1] = v.y; f[4*q+2] = v.z; f[4*q+3] = v.w;
  }

  // local chunk product
  Xf Q = make_T(f[0], st[0], ct[0], rr[0]);
#pragma unroll
  for (int s = 1; s < CHUNK; ++s)
    Q = compose(Q, make_T(f[s], st[s%3], ct[s%3], rr[s%3]));

  // wave-level inclusive scan (Hillis-Steele)
#pragma unroll
  for (int d = 1; d < 64; d <<= 1) {
    Xf O;
#pragma unroll
    for (int q = 0; q < 9; ++q) O.r[q] = __shfl_up(Q.r[q], d, 64);
#pragma unroll
    for (int q = 0; q < 3; ++q) O.p[q] = __shfl_up(Q.p[q], d, 64);
    if (t < d) set_identity(O);
    Q = compose(O, Q);
  }

  // exclusive prefix
  Xf E;
#pragma unroll
  for (int q = 0; q < 9; ++q) E.r[q] = __shfl_up(Q.r[q], 1, 64);
#pragma unroll
  for (int q = 0; q < 3; ++q) E.p[q] = __shfl_up(Q.p[q], 1, 64);
  if (t == 0) set_identity(E);

  // seed frame from carry0 = (e0, e1, e2)
  Xf S0;
  S0.r[0] = 0.f;                  S0.r[1] = 0.816496580927726f;   S0.r[2] = 0.5773502691896258f;
  S0.r[3] = -0.7071067811865475f; S0.r[4] = -0.4082482904638631f; S0.r[5] = 0.5773502691896258f;
  S0.r[6] = 0.7071067811865475f;  S0.r[7] = -0.4082482904638631f; S0.r[8] = 0.5773502691896258f;
  S0.p[0] = 0.f; S0.p[1] = 0.f; S0.p[2] = 1.f;

  Xf cur = compose(S0, E);

  float* op = out + (size_t)(t * CHUNK) * (BT * 3) + b * 3;
#pragma unroll
  for (int s = 0; s < CHUNK; ++s) {
    cur = compose(cur, make_T(f[s], st[s%3], ct[s%3], rr[s%3]));
    op[(size_t)s * (BT*3) + 0] = cur.p[0];
    op[(size_t)s * (BT*3) + 1] = cur.p[1];
    op[(size_t)s * (BT*3) + 2] = cur.p[2];
  }
}

// ---------- launch ---------------------------------------------------------
extern "C" void kernel_launch(void* const* d_in, const int* in_sizes, int n_in,
                              void* d_out, int out_size, void* d_ws, size_t ws_size,
                              hipStream_t stream) {
  const float* inp      = (const float*)d_in[0];
  const float* W        = (const float*)d_in[1];
  const float* bias     = (const float*)d_in[2];
  const float* alphabet = (const float*)d_in[3];
  const float* bl       = (const float*)d_in[4];
  const float* ba       = (const float*)d_in[5];
  float* out = (float*)d_out;
  float* phi = (float*)d_ws;    // (BT, NSTEP) floats = 786432 bytes

  k_phi<<<dim3((LSEQ*BT)/MT2), dim3(256), 0, stream>>>(inp, W, bias, alphabet, phi);
  k_scan<<<dim3(BT), dim3(64), 0, stream>>>(phi, bl, ba, out);
}

// Round 5
// 232.039 us; speedup vs baseline: 3.9091x; 1.1170x over previous
//
#include <hip/hip_runtime.h>
#include <math.h>

#define LSEQ  512
#define BT    128
#define INF   512
#define HH    60
#define NSTEP 1536   // 3*LSEQ
#define CHUNK 24     // steps per lane in scan kernel: 1536 / 64

#define MTILE 128    // rows per block (k_phi)
#define KTILE 64     // K staged per LDS tile
#define APAD  72     // bf16 row stride for A tiles: rows m,m+8 alias -> 2-way (free)

typedef __attribute__((ext_vector_type(8))) short bf16x8;
typedef __attribute__((ext_vector_type(4))) float floatx4;

// ---------- bf16 split helpers ---------------------------------------------
__device__ __forceinline__ unsigned short bf16_rn(float x) {
  unsigned u = __float_as_uint(x);
  return (unsigned short)((u + 0x7FFFu + ((u >> 16) & 1u)) >> 16);
}
__device__ __forceinline__ void split2(float x, unsigned short& h, unsigned short& l) {
  h = bf16_rn(x);
  float hf = __uint_as_float(((unsigned)h) << 16);
  l = bf16_rn(x - hf);
}

// ---------- W pre-conversion: fp32 -> (Wh, Wl) bf16 [64][512] --------------
__global__ __launch_bounds__(256) void k_wconv(
    const float* __restrict__ W, unsigned short* __restrict__ Wh,
    unsigned short* __restrict__ Wl) {
  const int idx = blockIdx.x * 256 + threadIdx.x;   // 0 .. 32767
  const int h = idx >> 9, k = idx & 511;
  float x = (h < HH) ? W[h * INF + k] : 0.f;
  unsigned short hb, lb; split2(x, hb, lb);
  Wh[idx] = hb; Wl[idx] = lb;
}

// ---------- kernel 1: split-bf16 MFMA GEMM + softmax + torsion angles ------
// Block: 256 thr = 4 waves, 128 rows x 64 cols (60 used). Wave w: rows
// [32w,32w+32) as 2 m-tiles x 4 n-tiles of mfma_f32_16x16x32_bf16.
// acc += Ah*Bh + Ah*Bl + Al*Bh  (split-fp32, ~2^-18 relative).
__global__ __launch_bounds__(256, 2) void k_phi(
    const float* __restrict__ inp, const unsigned short* __restrict__ Wh,
    const unsigned short* __restrict__ Wl, const float* __restrict__ bias,
    const float* __restrict__ alphabet, float* __restrict__ phi_out) {
  __shared__ unsigned short Ah[MTILE * APAD];   // 18432 B
  __shared__ unsigned short Al[MTILE * APAD];   // 18432 B
  __shared__ float sS[HH * 3], sC[HH * 3], sBias[64];

  const int tid  = threadIdx.x;
  const int lane = tid & 63;
  const int wid  = tid >> 6;
  const int c    = lane & 15;        // col-within-tile / frag row index
  const int quad = lane >> 4;        // 0..3
  const int row0 = blockIdx.x * MTILE;

  if (tid < HH * 3) { float a = alphabet[tid]; sS[tid] = __sinf(a); sC[tid] = __cosf(a); }
  if (tid >= 192 && tid < 256) { int n = tid - 192; sBias[n] = (n < HH) ? bias[n] : 0.f; }

  floatx4 acc[2][4];
#pragma unroll
  for (int mt = 0; mt < 2; ++mt)
#pragma unroll
    for (int nt = 0; nt < 4; ++nt) acc[mt][nt] = (floatx4){0.f, 0.f, 0.f, 0.f};

  for (int t = 0; t < INF / KTILE; ++t) {
    const int k0 = t * KTILE;
    // ---- stage A tile: 128 rows x 64 k fp32 -> bf16 h/l in LDS ----
#pragma unroll
    for (int i = 0; i < 8; ++i) {
      const int f4i = i * 256 + tid;          // 0..2047
      const int r   = f4i >> 4;               // row 0..127
      const int c4  = f4i & 15;               // float4-chunk 0..15
      float4 v = *(const float4*)(inp + (size_t)(row0 + r) * INF + k0 + 4 * c4);
      unsigned short h0,l0,h1,l1,h2,l2,h3,l3;
      split2(v.x, h0, l0); split2(v.y, h1, l1);
      split2(v.z, h2, l2); split2(v.w, h3, l3);
      uint2 ph = make_uint2((unsigned)h0 | ((unsigned)h1 << 16),
                            (unsigned)h2 | ((unsigned)h3 << 16));
      uint2 pl = make_uint2((unsigned)l0 | ((unsigned)l1 << 16),
                            (unsigned)l2 | ((unsigned)l3 << 16));
      *(uint2*)&Ah[r * APAD + 4 * c4] = ph;
      *(uint2*)&Al[r * APAD + 4 * c4] = pl;
    }
    __syncthreads();

#pragma unroll
    for (int ks = 0; ks < 2; ++ks) {
      const int kl = ks * 32;                 // k within tile
      const int kg = k0 + kl;                 // global k
      // B fragments from global (L2-hot, 128 KB total)
      bf16x8 Bh[4], Bl[4];
#pragma unroll
      for (int nt = 0; nt < 4; ++nt) {
        const int h = nt * 16 + c;
        Bh[nt] = *(const bf16x8*)(Wh + (size_t)h * INF + kg + quad * 8);
        Bl[nt] = *(const bf16x8*)(Wl + (size_t)h * INF + kg + quad * 8);
      }
      // A fragments from LDS
      bf16x8 Af[2], Alf[2];
#pragma unroll
      for (int mt = 0; mt < 2; ++mt) {
        const int m = wid * 32 + mt * 16 + c;
        Af[mt]  = *(const bf16x8*)(&Ah[m * APAD + kl + quad * 8]);
        Alf[mt] = *(const bf16x8*)(&Al[m * APAD + kl + quad * 8]);
      }
#pragma unroll
      for (int mt = 0; mt < 2; ++mt)
#pragma unroll
        for (int nt = 0; nt < 4; ++nt) {
          acc[mt][nt] = __builtin_amdgcn_mfma_f32_16x16x32_bf16(Af[mt],  Bh[nt], acc[mt][nt], 0, 0, 0);
          acc[mt][nt] = __builtin_amdgcn_mfma_f32_16x16x32_bf16(Af[mt],  Bl[nt], acc[mt][nt], 0, 0, 0);
          acc[mt][nt] = __builtin_amdgcn_mfma_f32_16x16x32_bf16(Alf[mt], Bh[nt], acc[mt][nt], 0, 0, 0);
        }
    }
    __syncthreads();
  }

  // ---- epilogue: C/D layout row = quad*4+reg, col = lane&15 ----
  // Per (mt, reg): row held by the 16 lanes of one quad; reduce over n via
  // shfl_xor masks 1,2,4,8 (stay within quad).
#pragma unroll
  for (int mt = 0; mt < 2; ++mt) {
#pragma unroll
    for (int reg = 0; reg < 4; ++reg) {
      float lg[4];  bool val[4];
#pragma unroll
      for (int nt = 0; nt < 4; ++nt) {
        const int n = nt * 16 + c;
        val[nt] = (n < HH);
        lg[nt] = acc[mt][nt][reg] + sBias[n];
      }
      float m = -1e30f;
#pragma unroll
      for (int nt = 0; nt < 4; ++nt) if (val[nt]) m = fmaxf(m, lg[nt]);
#pragma unroll
      for (int d = 1; d < 16; d <<= 1) m = fmaxf(m, __shfl_xor(m, d, 64));

      float s0=0.f,c0=0.f,s1=0.f,c1=0.f,s2=0.f,c2=0.f;
#pragma unroll
      for (int nt = 0; nt < 4; ++nt) {
        const int n = nt * 16 + c;
        float e = val[nt] ? __expf(lg[nt] - m) : 0.f;
        s0 = fmaf(e, sS[n*3+0], s0);  c0 = fmaf(e, sC[n*3+0], c0);
        s1 = fmaf(e, sS[n*3+1], s1);  c1 = fmaf(e, sC[n*3+1], c1);
        s2 = fmaf(e, sS[n*3+2], s2);  c2 = fmaf(e, sC[n*3+2], c2);
      }
#pragma unroll
      for (int d = 1; d < 16; d <<= 1) {
        s0 += __shfl_xor(s0, d, 64);  c0 += __shfl_xor(c0, d, 64);
        s1 += __shfl_xor(s1, d, 64);  c1 += __shfl_xor(c1, d, 64);
        s2 += __shfl_xor(s2, d, 64);  c2 += __shfl_xor(c2, d, 64);
      }
      if (c == 0) {
        const int row = row0 + wid * 32 + mt * 16 + quad * 4 + reg;
        const int l  = row >> 7;        // / BT
        const int bb = row & 127;       // % BT
        float* pp = phi_out + (size_t)bb * NSTEP + 3 * l;
        pp[0] = atan2f(s0, c0);
        pp[1] = atan2f(s1, c1);
        pp[2] = atan2f(s2, c2);
      }
    }
  }
}

// ---------- rigid transform (3x3 rotation row-major + translation) ----------
struct Xf { float r[9]; float p[3]; };

__device__ __forceinline__ Xf compose(const Xf& A, const Xf& B) {
  Xf o;
#pragma unroll
  for (int i = 0; i < 3; ++i) {
#pragma unroll
    for (int j = 0; j < 3; ++j) {
      o.r[i*3+j] = fmaf(A.r[i*3+0], B.r[0+j],
                   fmaf(A.r[i*3+1], B.r[3+j],
                        A.r[i*3+2] * B.r[6+j]));
    }
    o.p[i] = fmaf(A.r[i*3+0], B.p[0],
             fmaf(A.r[i*3+1], B.p[1],
             fmaf(A.r[i*3+2], B.p[2], A.p[i])));
  }
  return o;
}

__device__ __forceinline__ Xf make_T(float phi, float st, float ct, float r) {
  float sp = __sinf(phi), cp = __cosf(phi);
  Xf T;
  T.r[0] = ct;      T.r[1] = -st;     T.r[2] = 0.f;
  T.r[3] = cp * st; T.r[4] = ct * cp; T.r[5] = -sp;
  T.r[6] = sp * st; T.r[7] = ct * sp; T.r[8] = cp;
  T.p[0] = r * ct;  T.p[1] = r * T.r[3]; T.p[2] = r * T.r[6];
  return T;
}

__device__ __forceinline__ void set_identity(Xf& X) {
  X.r[0]=1.f; X.r[1]=0.f; X.r[2]=0.f;
  X.r[3]=0.f; X.r[4]=1.f; X.r[5]=0.f;
  X.r[6]=0.f; X.r[7]=0.f; X.r[8]=1.f;
  X.p[0]=0.f; X.p[1]=0.f; X.p[2]=0.f;
}

// ---------- kernel 2: parallel rigid-transform scan ------------------------
__global__ __launch_bounds__(64) void k_scan(
    const float* __restrict__ phi, const float* __restrict__ bl,
    const float* __restrict__ ba, float* __restrict__ out) {
  const int b = blockIdx.x;       // chain 0..127
  const int t = threadIdx.x;      // lane 0..63

  float st[3], ct[3], rr[3];
#pragma unroll
  for (int j = 0; j < 3; ++j) {
    float a = ba[j];
    st[j] = __sinf(a); ct[j] = __cosf(a); rr[j] = bl[j];
  }

  float f[CHUNK];
  const float4* ph4 = (const float4*)(phi + (size_t)b * NSTEP + t * CHUNK);
#pragma unroll
  for (int q = 0; q < CHUNK/4; ++q) {
    float4 v = ph4[q];
    f[4*q+0] = v.x; f[4*q+1] = v.y; f[4*q+2] = v.z; f[4*q+3] = v.w;
  }

  Xf Q = make_T(f[0], st[0], ct[0], rr[0]);
#pragma unroll
  for (int s = 1; s < CHUNK; ++s)
    Q = compose(Q, make_T(f[s], st[s%3], ct[s%3], rr[s%3]));

#pragma unroll
  for (int d = 1; d < 64; d <<= 1) {
    Xf O;
#pragma unroll
    for (int q = 0; q < 9; ++q) O.r[q] = __shfl_up(Q.r[q], d, 64);
#pragma unroll
    for (int q = 0; q < 3; ++q) O.p[q] = __shfl_up(Q.p[q], d, 64);
    if (t < d) set_identity(O);
    Q = compose(O, Q);
  }

  Xf E;
#pragma unroll
  for (int q = 0; q < 9; ++q) E.r[q] = __shfl_up(Q.r[q], 1, 64);
#pragma unroll
  for (int q = 0; q < 3; ++q) E.p[q] = __shfl_up(Q.p[q], 1, 64);
  if (t == 0) set_identity(E);

  Xf S0;
  S0.r[0] = 0.f;                  S0.r[1] = 0.816496580927726f;   S0.r[2] = 0.5773502691896258f;
  S0.r[3] = -0.7071067811865475f; S0.r[4] = -0.4082482904638631f; S0.r[5] = 0.5773502691896258f;
  S0.r[6] = 0.7071067811865475f;  S0.r[7] = -0.4082482904638631f; S0.r[8] = 0.5773502691896258f;
  S0.p[0] = 0.f; S0.p[1] = 0.f; S0.p[2] = 1.f;

  Xf cur = compose(S0, E);

  float* op = out + (size_t)(t * CHUNK) * (BT * 3) + b * 3;
#pragma unroll
  for (int s = 0; s < CHUNK; ++s) {
    cur = compose(cur, make_T(f[s], st[s%3], ct[s%3], rr[s%3]));
    op[(size_t)s * (BT*3) + 0] = cur.p[0];
    op[(size_t)s * (BT*3) + 1] = cur.p[1];
    op[(size_t)s * (BT*3) + 2] = cur.p[2];
  }
}

// ---------- launch ---------------------------------------------------------
extern "C" void kernel_launch(void* const* d_in, const int* in_sizes, int n_in,
                              void* d_out, int out_size, void* d_ws, size_t ws_size,
                              hipStream_t stream) {
  const float* inp      = (const float*)d_in[0];
  const float* W        = (const float*)d_in[1];
  const float* bias     = (const float*)d_in[2];
  const float* alphabet = (const float*)d_in[3];
  const float* bl       = (const float*)d_in[4];
  const float* ba       = (const float*)d_in[5];
  float* out = (float*)d_out;

  float* phi = (float*)d_ws;                                   // 786432 B
  unsigned short* Wh = (unsigned short*)((char*)d_ws + 786432); // 65536 B
  unsigned short* Wl = Wh + 64 * INF;                           // 65536 B

  k_wconv<<<dim3(128), dim3(256), 0, stream>>>(W, Wh, Wl);
  k_phi<<<dim3((LSEQ*BT)/MTILE), dim3(256), 0, stream>>>(inp, Wh, Wl, bias, alphabet, phi);
  k_scan<<<dim3(BT), dim3(64), 0, stream>>>(phi, bl, ba, out);
}